// Round 6
// baseline (321.810 us; speedup 1.0000x reference)
//
#include <hip/hip_runtime.h>

// Delta differential encoding with residual carry, per-(B,C) row scan over T.
// x: [32, 2048, 512] f32, rows = 65536 contiguous rows of T=512.
// One thread per row; 64-float chunks double-buffered in registers for ILP
// (grid-capped at ~4 waves/CU, so latency hiding must come from in-flight loads).

#define T_LEN 512

constexpr int BLOCK  = 256;
constexpr int CHUNK  = 64;              // floats per pipeline stage
constexpr int NV     = CHUNK / 4;       // 16 float4 per chunk
constexpr int NCHUNK = T_LEN / CHUNK;   // 8 chunks per row

__global__ __launch_bounds__(BLOCK) void delta_scan_kernel(
    const float* __restrict__ x,
    const float* __restrict__ thrp,
    float* __restrict__ out,
    int rows)
{
    const int row = blockIdx.x * BLOCK + threadIdx.x;
    if (row >= rows) return;

    // threshold clamp to [1/64, inf) — uniform, becomes scalar load
    const float thr = fmaxf(thrp[0], 0.015625f);

    const float4* __restrict__ xv =
        reinterpret_cast<const float4*>(x) + (size_t)row * (T_LEN / 4);
    float4* __restrict__ ov =
        reinterpret_cast<float4*>(out) + (size_t)row * (T_LEN / 4);

    float4 bufA[NV], bufB[NV];

    // prologue: chunk 0 in flight
#pragma unroll
    for (int i = 0; i < NV; ++i) bufA[i] = xv[i];

    float pre = 0.0f, res = 0.0f;

    // fully unrolled so buffer selection is compile-time (no scratch spill)
#pragma unroll
    for (int c = 0; c < NCHUNK; ++c) {
        float4* curb = (c & 1) ? bufB : bufA;
        float4* nxtb = (c & 1) ? bufA : bufB;

        // prefetch next chunk while computing this one
        if (c + 1 < NCHUNK) {
#pragma unroll
            for (int i = 0; i < NV; ++i) nxtb[i] = xv[(c + 1) * NV + i];
        }

#pragma unroll
        for (int i = 0; i < NV; ++i) {
            float4 v = curb[i];
            float4 q;

            // element-wise scan steps; carry chain per element is
            // add -> cmp -> cndmask (the (v - pre) diff is off-chain).
            {
                float d   = (v.x - pre) + res;     // exact ref order
                bool  big = fabsf(d) >= thr;
                float y   = big ? d : 0.0f;
                res       = big ? 0.0f : d;        // == d - y bit-exactly
                pre       = v.x;
                q.x = floorf(y * 64.0f) * 0.015625f;
            }
            {
                float d   = (v.y - pre) + res;
                bool  big = fabsf(d) >= thr;
                float y   = big ? d : 0.0f;
                res       = big ? 0.0f : d;
                pre       = v.y;
                q.y = floorf(y * 64.0f) * 0.015625f;
            }
            {
                float d   = (v.z - pre) + res;
                bool  big = fabsf(d) >= thr;
                float y   = big ? d : 0.0f;
                res       = big ? 0.0f : d;
                pre       = v.z;
                q.z = floorf(y * 64.0f) * 0.015625f;
            }
            {
                float d   = (v.w - pre) + res;
                bool  big = fabsf(d) >= thr;
                float y   = big ? d : 0.0f;
                res       = big ? 0.0f : d;
                pre       = v.w;
                q.w = floorf(y * 64.0f) * 0.015625f;
            }

            ov[c * NV + i] = q;
        }
    }
}

extern "C" void kernel_launch(void* const* d_in, const int* in_sizes, int n_in,
                              void* d_out, int out_size, void* d_ws, size_t ws_size,
                              hipStream_t stream)
{
    const float* x    = (const float*)d_in[0];
    const float* thrp = (const float*)d_in[1];
    float*       out  = (float*)d_out;

    const int rows = in_sizes[0] / T_LEN;           // 65536
    const int grid = (rows + BLOCK - 1) / BLOCK;    // 256

    delta_scan_kernel<<<grid, BLOCK, 0, stream>>>(x, thrp, out, rows);
}

// Round 7
// 243.149 us; speedup vs baseline: 1.3235x; 1.3235x over previous
//
#include <hip/hip_runtime.h>

// Delta scan with residual carry, one thread per row (65536 rows x 512 floats).
//
// R6 finding: direct per-thread float4 stores to 2048B-strided rows caused
// 2.31x HBM write amplification (310 MB vs 134 MB ideal) - 64 partially
// written lines per store instruction, evicted from the 4MB/XCD L2 before
// completion. Fix: stage output chunks in LDS, store 256B-contiguous
// segments per 16-lane group (full 128B lines at HBM).
// Read path stays direct-from-global (measured amplification only 1.16x,
// input is L3-resident).

#define T_LEN 512

constexpr int BLOCK   = 256;            // threads per block = rows per block
constexpr int ROWS_PB = 256;
constexpr int CF      = 64;             // chunk floats per row
constexpr int CV      = CF / 4;         // 16 float4 per row-chunk
constexpr int NCHUNK  = T_LEN / CF;     // 8 chunks
constexpr int NROUND  = ROWS_PB * CV / BLOCK;  // 16 stage-out rounds

__global__ __launch_bounds__(BLOCK) void delta_scan_kernel(
    const float* __restrict__ x,
    const float* __restrict__ thrp,
    float* __restrict__ out)
{
    // 256 rows x 16 float4 = 64 KB. XOR swizzle (no padding) keeps both
    // access phases at the minimal 8-lanes-per-bank-quad.
    __shared__ float4 lds[ROWS_PB * CV];

    const int tid  = threadIdx.x;
    const int row0 = blockIdx.x * ROWS_PB;

    // threshold clamp to [1/64, inf) - uniform scalar
    const float thr = fmaxf(thrp[0], 0.015625f);

    const float4* __restrict__ xv = reinterpret_cast<const float4*>(x);
    float4* __restrict__       ov = reinterpret_cast<float4*>(out);

    // this thread's row, in float4 units
    const size_t rbase = (size_t)(row0 + tid) * (T_LEN / 4);

    float pre = 0.0f, res = 0.0f;

#pragma unroll
    for (int c = 0; c < NCHUNK; ++c) {
        // ---- phase 1: bulk-load row chunk (16 loads in flight), scan,
        //      deposit to LDS swizzled ----
        float4 v[CV];
#pragma unroll
        for (int i = 0; i < CV; ++i) v[i] = xv[rbase + c * CV + i];

#pragma unroll
        for (int i = 0; i < CV; ++i) {
            float4 q;
            // exact reference op order: d = (x - pre) + res;
            // y = |d|>=thr ? d : 0; res = d - y (== big?0:d bit-exactly);
            // out = floor(y*64) * 2^-6 (power-of-2 scaling is exact)
            { float d=(v[i].x-pre)+res; bool b=fabsf(d)>=thr; float y=b?d:0.0f;
              res=b?0.0f:d; pre=v[i].x; q.x=floorf(y*64.0f)*0.015625f; }
            { float d=(v[i].y-pre)+res; bool b=fabsf(d)>=thr; float y=b?d:0.0f;
              res=b?0.0f:d; pre=v[i].y; q.y=floorf(y*64.0f)*0.015625f; }
            { float d=(v[i].z-pre)+res; bool b=fabsf(d)>=thr; float y=b?d:0.0f;
              res=b?0.0f:d; pre=v[i].z; q.z=floorf(y*64.0f)*0.015625f; }
            { float d=(v[i].w-pre)+res; bool b=fabsf(d)>=thr; float y=b?d:0.0f;
              res=b?0.0f:d; pre=v[i].w; q.w=floorf(y*64.0f)*0.015625f; }

            lds[tid * CV + (i ^ (tid & 7))] = q;
        }
        __syncthreads();

        // ---- phase 2: coalesced stage-out. Each 16-lane group stores one
        //      256B-contiguous segment (two full 128B lines). ----
#pragma unroll
        for (int k = 0; k < NROUND; ++k) {
            const int rr = k * (BLOCK / CV) + (tid >> 4);  // row within block
            const int jj = tid & (CV - 1);                 // f4 within chunk
            const float4 t4 = lds[rr * CV + (jj ^ (rr & 7))];
            ov[(size_t)(row0 + rr) * (T_LEN / 4) + c * CV + jj] = t4;
        }
        __syncthreads();   // protect LDS reuse next chunk
    }
}

extern "C" void kernel_launch(void* const* d_in, const int* in_sizes, int n_in,
                              void* d_out, int out_size, void* d_ws, size_t ws_size,
                              hipStream_t stream)
{
    const float* x    = (const float*)d_in[0];
    const float* thrp = (const float*)d_in[1];
    float*       out  = (float*)d_out;

    const int rows = in_sizes[0] / T_LEN;          // 65536
    const int grid = rows / ROWS_PB;               // 256 blocks, 1 per CU

    delta_scan_kernel<<<grid, BLOCK, 0, stream>>>(x, thrp, out);
}

// Round 8
// 240.537 us; speedup vs baseline: 1.3379x; 1.0109x over previous
//
#include <hip/hip_runtime.h>

// Delta scan with residual carry, one thread per row (65536 rows x 512 f32).
//
// R6: direct strided stores -> 2.31x write amplification. Fixed in R7 via
// LDS transpose + coalesced 256B-segment stores (WRITE_SIZE 310->131 MB).
// R7: still 124 us at only 1.75 TB/s -- serialization-bound: per chunk,
// load-wait -> scan -> barrier -> store -> barrier(vmcnt(0) drain), with
// only 1 wave/SIMD (grid-capped) there is no overlap across phases.
//
// R8 structure: per-WAVE private LDS tile (64 rows x 16 f4 = 16 KB/wave),
// NO __syncthreads anywhere (wave-lockstep + in-order DS pipe make
// write->read->overwrite safe with compiler lgkmcnt waits). Stores never
// drain at a barrier; 4 waves/CU phase-shift naturally. Register
// double-buffer prefetches chunk c+1 before the ~800-cycle scan of chunk c.
// __launch_bounds__(256,1): 1 wave/SIMD is all the grid gives -> let the
// allocator use up to 512 VGPR so the prefetch is not sunk (R6: VGPR=40
// proved the compiler deleted the pipeline under pressure heuristics).

#define T_LEN 512

constexpr int BLOCK   = 256;
constexpr int WAVE    = 64;
constexpr int CV      = 16;               // float4 per 64-float chunk
constexpr int NCHUNK  = T_LEN / (CV * 4); // 8

__global__ __launch_bounds__(BLOCK, 1) void delta_scan_kernel(
    const float* __restrict__ x,
    const float* __restrict__ thrp,
    float* __restrict__ out)
{
    // per-wave 16 KB tile; XOR swizzle (measured 0 conflicts in R7)
    __shared__ float4 lds[BLOCK / WAVE][WAVE * CV];

    const int tid  = threadIdx.x;
    const int wid  = tid >> 6;
    const int lane = tid & 63;
    float4* __restrict__ wlds = lds[wid];

    const int row   = blockIdx.x * BLOCK + tid;        // this thread's row
    const int wrow0 = blockIdx.x * BLOCK + wid * WAVE; // wave's first row

    const float thr = fmaxf(thrp[0], 0.015625f);

    const float4* __restrict__ xv = reinterpret_cast<const float4*>(x);
    float4* __restrict__       ov = reinterpret_cast<float4*>(out);
    const size_t rbase = (size_t)row * (T_LEN / 4);

    float pre = 0.0f, res = 0.0f;
    float4 va[CV], vb[CV];

    // prologue: chunk 0 in flight
#pragma unroll
    for (int i = 0; i < CV; ++i) va[i] = xv[rbase + i];

#pragma unroll
    for (int c = 0; c < NCHUNK; ++c) {
        float4* cur = (c & 1) ? vb : va;
        float4* nxt = (c & 1) ? va : vb;

        // prefetch chunk c+1; latency hides under the scan's dependent chain
        if (c + 1 < NCHUNK) {
#pragma unroll
            for (int i = 0; i < CV; ++i) nxt[i] = xv[rbase + (c + 1) * CV + i];
        }

        // scan chunk c, deposit swizzled into the wave tile
#pragma unroll
        for (int i = 0; i < CV; ++i) {
            float4 v = cur[i];
            float4 q;
            // exact reference op order: d=(x-pre)+res; y=|d|>=thr?d:0;
            // res=d-y (==big?0:d bit-exact); out=floor(y*64)*2^-6 (exact)
            { float d=(v.x-pre)+res; bool b=fabsf(d)>=thr; float y=b?d:0.0f;
              res=b?0.0f:d; pre=v.x; q.x=floorf(y*64.0f)*0.015625f; }
            { float d=(v.y-pre)+res; bool b=fabsf(d)>=thr; float y=b?d:0.0f;
              res=b?0.0f:d; pre=v.y; q.y=floorf(y*64.0f)*0.015625f; }
            { float d=(v.z-pre)+res; bool b=fabsf(d)>=thr; float y=b?d:0.0f;
              res=b?0.0f:d; pre=v.z; q.z=floorf(y*64.0f)*0.015625f; }
            { float d=(v.w-pre)+res; bool b=fabsf(d)>=thr; float y=b?d:0.0f;
              res=b?0.0f:d; pre=v.w; q.w=floorf(y*64.0f)*0.015625f; }

            wlds[lane * CV + (i ^ (lane & 7))] = q;
        }

        // stage-out: wave-lockstep, no barrier. 16 rounds; each 16-lane
        // group stores one 256B-contiguous segment (2 full 128B lines).
#pragma unroll
        for (int k = 0; k < 16; ++k) {
            const int rr = k * 4 + (lane >> 4);   // row within wave tile
            const int jj = lane & 15;             // f4 within chunk
            const float4 t4 = wlds[rr * CV + (jj ^ (rr & 7))];
            ov[(size_t)(wrow0 + rr) * (T_LEN / 4) + c * CV + jj] = t4;
        }
        // next chunk's LDS writes follow in program order; DS pipe is
        // in-order per wave -> no WAR hazard, no barrier needed.
    }
}

extern "C" void kernel_launch(void* const* d_in, const int* in_sizes, int n_in,
                              void* d_out, int out_size, void* d_ws, size_t ws_size,
                              hipStream_t stream)
{
    const float* x    = (const float*)d_in[0];
    const float* thrp = (const float*)d_in[1];
    float*       out  = (float*)d_out;

    const int rows = in_sizes[0] / T_LEN;   // 65536
    const int grid = rows / BLOCK;          // 256 blocks

    delta_scan_kernel<<<grid, BLOCK, 0, stream>>>(x, thrp, out);
}

// Round 9
// 239.733 us; speedup vs baseline: 1.3424x; 1.0034x over previous
//
#include <hip/hip_runtime.h>

// Delta scan with residual carry, one thread per row (65536 rows x 512 f32).
//
// Ladder: R6 direct strided stores = 2.31x write amp (310 MB). R7 LDS
// transpose + coalesced stores = ideal 131 MB but barrier-serialized
// (124 us). R8 barrier-free wave-private tiles = 87 us, but VGPR=96
// proved the compiler sank the register double-buffer (va+vb=128 VGPR
// alone), so waves run with no loads outstanding ~90% of the time
// (2.4 TB/s, VALUBusy 7%).
//
// R9: keep memory outstanding at all times.
//  - prefetch depth 2: three rotating reg buffers (192 VGPR data)
//  - asm volatile("" ::: "memory") after each load burst pins the issue
//    point (compiler cannot sink loads past a memory clobber)
//  - stage-out deferred one chunk via ping-pong LDS tiles: stores of
//    chunk c-1 issue BEFORE the scan of chunk c -> ds_read+store stream
//    overlaps the 768-cycle scan chain instead of serializing after it
//  - still ZERO barriers (wave-private tiles, in-order DS pipe; WAR
//    between iter-c reads and iter-c+1 writes is safe per R8, absmax=0)

#define T_LEN 512

constexpr int BLOCK  = 256;
constexpr int WAVE   = 64;
constexpr int CV     = 16;               // float4 per 64-float chunk
constexpr int NCHUNK = T_LEN / (CV * 4); // 8

__global__ __launch_bounds__(BLOCK, 1) void delta_scan_kernel(
    const float* __restrict__ x,
    const float* __restrict__ thrp,
    float* __restrict__ out)
{
    // 2 ping-pong tiles x 4 waves x 16 KB = 128 KB (fits 160 KB/CU, 1 block/CU)
    __shared__ float4 lds[2][BLOCK / WAVE][WAVE * CV];

    const int tid  = threadIdx.x;
    const int wid  = tid >> 6;
    const int lane = tid & 63;

    const int row   = blockIdx.x * BLOCK + tid;
    const int wrow0 = blockIdx.x * BLOCK + wid * WAVE;

    const float thr = fmaxf(thrp[0], 0.015625f);

    const float4* __restrict__ xv = reinterpret_cast<const float4*>(x);
    float4* __restrict__       ov = reinterpret_cast<float4*>(out);
    const size_t rbase = (size_t)row * (T_LEN / 4);

    float4 bA[CV], bB[CV], bC[CV];
    float pre = 0.0f, res = 0.0f;

    // prologue: chunks 0 and 1 in flight
#pragma unroll
    for (int i = 0; i < CV; ++i) bA[i] = xv[rbase + i];
#pragma unroll
    for (int i = 0; i < CV; ++i) bB[i] = xv[rbase + CV + i];
    asm volatile("" ::: "memory");   // pin load issue point (defeat sinking)

#pragma unroll
    for (int c = 0; c < NCHUNK; ++c) {
        // rotating buffer selection folds at compile time (loop fully unrolled)
        float4* cur = (c % 3 == 0) ? bA : ((c % 3 == 1) ? bB : bC);
        float4* nx2 = ((c + 2) % 3 == 0) ? bA : (((c + 2) % 3 == 1) ? bB : bC);

        // issue loads for chunk c+2 first; they stay outstanding across
        // the store stream and the scan below
        if (c + 2 < NCHUNK) {
#pragma unroll
            for (int i = 0; i < CV; ++i) nx2[i] = xv[rbase + (c + 2) * CV + i];
            asm volatile("" ::: "memory");
        }

        // stage-out chunk c-1 (written to tile[(c-1)&1] last iteration):
        // 16 rounds, each 16-lane group stores a 256B-contiguous segment
        if (c > 0) {
            const float4* pt = lds[(c - 1) & 1][wid];
#pragma unroll
            for (int k = 0; k < 16; ++k) {
                const int rr = k * 4 + (lane >> 4);
                const int jj = lane & 15;
                const float4 t4 = pt[rr * CV + (jj ^ (rr & 7))];
                ov[(size_t)(wrow0 + rr) * (T_LEN / 4) + (c - 1) * CV + jj] = t4;
            }
        }

        // scan chunk c -> tile[c&1] (swizzled; 0 conflicts measured R7/R8)
        float4* wt = lds[c & 1][wid];
#pragma unroll
        for (int i = 0; i < CV; ++i) {
            float4 v = cur[i];
            float4 q;
            // exact reference op order: d=(x-pre)+res; y=|d|>=thr?d:0;
            // res=d-y (==big?0:d bit-exact); out=floor(y*64)*2^-6 (exact)
            { float d=(v.x-pre)+res; bool b=fabsf(d)>=thr; float y=b?d:0.0f;
              res=b?0.0f:d; pre=v.x; q.x=floorf(y*64.0f)*0.015625f; }
            { float d=(v.y-pre)+res; bool b=fabsf(d)>=thr; float y=b?d:0.0f;
              res=b?0.0f:d; pre=v.y; q.y=floorf(y*64.0f)*0.015625f; }
            { float d=(v.z-pre)+res; bool b=fabsf(d)>=thr; float y=b?d:0.0f;
              res=b?0.0f:d; pre=v.z; q.z=floorf(y*64.0f)*0.015625f; }
            { float d=(v.w-pre)+res; bool b=fabsf(d)>=thr; float y=b?d:0.0f;
              res=b?0.0f:d; pre=v.w; q.w=floorf(y*64.0f)*0.015625f; }

            wt[lane * CV + (i ^ (lane & 7))] = q;
        }
    }

    // epilogue: store chunk 7 from tile[1]
    {
        const float4* pt = lds[(NCHUNK - 1) & 1][wid];
#pragma unroll
        for (int k = 0; k < 16; ++k) {
            const int rr = k * 4 + (lane >> 4);
            const int jj = lane & 15;
            const float4 t4 = pt[rr * CV + (jj ^ (rr & 7))];
            ov[(size_t)(wrow0 + rr) * (T_LEN / 4) + (NCHUNK - 1) * CV + jj] = t4;
        }
    }
}

extern "C" void kernel_launch(void* const* d_in, const int* in_sizes, int n_in,
                              void* d_out, int out_size, void* d_ws, size_t ws_size,
                              hipStream_t stream)
{
    const float* x    = (const float*)d_in[0];
    const float* thrp = (const float*)d_in[1];
    float*       out  = (float*)d_out;

    const int rows = in_sizes[0] / T_LEN;   // 65536
    const int grid = rows / BLOCK;          // 256 blocks, 1 per CU

    delta_scan_kernel<<<grid, BLOCK, 0, stream>>>(x, thrp, out);
}